// Round 10
// baseline (144.446 us; speedup 1.0000x reference)
//
#include <hip/hip_runtime.h>
#include <cmath>

#define Bn 32
#define Hn 512
#define Wn 512
#define TW 32
#define TH 32
#define RH 40
#define RWE 40                        // staged row stride in floats
#define NTILES 8192
#define NBLK 1024
#define TPT (NTILES / NBLK)           // 8 tiles per block

struct GaussW { float g[9]; };

// double-buffered cross-tile prefetch set (registers)
struct Pref {
    float4 i0, v0, f0;    // chunk 0: ir, vis, fus
    float4 i1, v1, f1;    // chunk 1 (threads t<144 only)
    float mk0, mk1, mk2, mk3;
    int ok0, ok1;
};

__device__ __forceinline__ void prefetch_tile(
    int tile, int cx, int r0, bool has1,
    int ry0, int p0, int ry1, int p1,
    const float* __restrict__ ir, const float* __restrict__ vis,
    const float* __restrict__ fus, const float* __restrict__ mask,
    Pref& P)
{
    const int rem = tile & 255;
    const int y0 = (rem >> 4) * TH;
    const int x0 = (rem & 15) * TW;
    const size_t base = (size_t)(tile >> 8) * (size_t)(Hn * Wn);

    // halo = 4 px = exactly one float4 -> chunks are all-or-nothing valid
    int gy0 = y0 + ry0 - 4, gx0 = x0 + p0 * 4 - 4;
    P.ok0 = ((unsigned)gy0 < (unsigned)Hn) &&
            !((x0 == 0) && (p0 == 0)) && !((x0 == Wn - TW) && (p0 == 9));
    size_t o0 = P.ok0 ? (base + (size_t)gy0 * Wn + gx0) : 0;
    P.i0 = *(const float4*)(ir + o0);
    P.v0 = *(const float4*)(vis + o0);
    P.f0 = *(const float4*)(fus + o0);

    int gy1 = y0 + ry1 - 4, gx1 = x0 + p1 * 4 - 4;
    P.ok1 = has1 && ((unsigned)gy1 < (unsigned)Hn) &&
            !((x0 == 0) && (p1 == 0)) && !((x0 == Wn - TW) && (p1 == 9));
    size_t o1 = P.ok1 ? (base + (size_t)gy1 * Wn + gx1) : 0;
    P.i1 = *(const float4*)(ir + o1);
    P.v1 = *(const float4*)(vis + o1);
    P.f1 = *(const float4*)(fus + o1);

    // mask for this thread's 4 output pixels (rows 4*r0+k, col cx)
    const size_t mb = base + (size_t)(y0 + 4 * r0) * Wn + (x0 + cx);
    P.mk0 = mask[mb];
    P.mk1 = mask[mb + Wn];
    P.mk2 = mask[mb + 2 * Wn];
    P.mk3 = mask[mb + 3 * Wn];
}

__device__ __forceinline__ void stage_write(
    const Pref& P, bool has1, int ry0, int p0, int ry1, int p1,
    float* s_ir, float* s_vi, float* s_fu)
{
    const float4 z = make_float4(0.f, 0.f, 0.f, 0.f);
    int d0 = ry0 * RWE + p0 * 4;
    *(float4*)&s_ir[d0] = P.ok0 ? P.i0 : z;
    *(float4*)&s_vi[d0] = P.ok0 ? P.v0 : z;
    *(float4*)&s_fu[d0] = P.ok0 ? P.f0 : z;
    if (has1) {
        int d1 = ry1 * RWE + p1 * 4;
        *(float4*)&s_ir[d1] = P.ok1 ? P.i1 : z;
        *(float4*)&s_vi[d1] = P.ok1 ? P.v1 : z;
        *(float4*)&s_fu[d1] = P.ok1 ? P.f1 : z;
    }
}

__device__ __forceinline__ void phase_B(
    int t, const GaussW& gw,
    const float* s_ir, const float* s_vi, const float* s_fu,
    float4* s_h1, float2* s_h2)
{
    // 320 tasks: (row ry 0..39) x (col-group g 0..7); 4 h-pixels per task
    for (int task = t; task < 320; task += 256) {
        int ry = task >> 3, g = task & 7;
        int fo = ry * RWE + g * 4;
        float4 A0 = *(const float4*)&s_ir[fo];
        float4 A1 = *(const float4*)&s_ir[fo + 4];
        float4 A2 = *(const float4*)&s_ir[fo + 8];
        float4 F0 = *(const float4*)&s_fu[fo];
        float4 F1 = *(const float4*)&s_fu[fo + 4];
        float4 F2 = *(const float4*)&s_fu[fo + 8];
        float4 V0 = *(const float4*)&s_vi[fo];
        float4 V1 = *(const float4*)&s_vi[fo + 4];
        float4 V2 = *(const float4*)&s_vi[fo + 8];
        float ira[12] = {A0.x,A0.y,A0.z,A0.w, A1.x,A1.y,A1.z,A1.w, A2.x,A2.y,A2.z,A2.w};
        float fua[12] = {F0.x,F0.y,F0.z,F0.w, F1.x,F1.y,F1.z,F1.w, F2.x,F2.y,F2.z,F2.w};
        float via[12] = {V0.x,V0.y,V0.z,V0.w, V1.x,V1.y,V1.z,V1.w, V2.x,V2.y,V2.z,V2.w};
        #pragma unroll
        for (int m = 0; m < 4; ++m) {
            float hbi = 0.f, hbv = 0.f, hgi = 0.f, hgv = 0.f, h2i = 0.f, h2v = 0.f;
            #pragma unroll
            for (int dx = 0; dx < 9; ++dx) {
                float a = ira[m + dx], f = fua[m + dx], v = via[m + dx];
                float di = a - f, dv = v - f;
                hbi = fmaf(di, di, hbi);
                hbv = fmaf(dv, dv, hbv);
                float gg = gw.g[dx];
                hgi = fmaf(gg, a, hgi);
                hgv = fmaf(gg, v, hgv);
                h2i = fmaf(gg, a * a, h2i);
                h2v = fmaf(gg, v * v, h2v);
            }
            int ho = ry * TW + g * 4 + m;
            s_h1[ho] = make_float4(hbi, hbv, hgi, hgv);
            s_h2[ho] = make_float2(h2i, h2v);
        }
    }
}

__device__ __forceinline__ void phase_C(
    int cx, int r0, const GaussW& gw, const Pref& P,
    const float4* s_h1, const float2* s_h2, float& acc)
{
    // thread -> 4 consecutive output rows 4*r0+k at column cx; 12 shared taps
    float bi[4] = {0,0,0,0}, bv[4] = {0,0,0,0};
    float mi[4] = {0,0,0,0}, mv[4] = {0,0,0,0};
    float qi[4] = {0,0,0,0}, qv[4] = {0,0,0,0};
    int hb = (r0 * 4) * TW + cx;
    #pragma unroll
    for (int j = 0; j < 12; ++j) {
        float4 h1 = s_h1[hb + j * TW];
        float2 h2 = s_h2[hb + j * TW];
        #pragma unroll
        for (int k = 0; k < 4; ++k) {
            int d = j - k;
            if (d >= 0 && d <= 8) {       // compile-time predicate
                float gg = gw.g[d];
                bi[k] += h1.x;  bv[k] += h1.y;
                mi[k] = fmaf(gg, h1.z, mi[k]);
                mv[k] = fmaf(gg, h1.w, mv[k]);
                qi[k] = fmaf(gg, h2.x, qi[k]);
                qv[k] = fmaf(gg, h2.y, qv[k]);
            }
        }
    }
    #pragma unroll
    for (int k = 0; k < 4; ++k) {
        float var_i = qi[k] - mi[k] * mi[k];
        float var_v = qv[k] - mv[k] * mv[k];
        float m1 = (var_i - var_v > 0.f) ? 1.f : 0.f;
        float mkv = (k == 0) ? P.mk0 : (k == 1) ? P.mk1 : (k == 2) ? P.mk2 : P.mk3;
        float sel = (m1 + mkv > 0.f) ? 1.f : 0.f;
        acc += sel * (bi[k] * (1.f / 81.f)) + (1.f - sel) * (bv[k] * (1.f / 81.f));
    }
}

// SoA planes + separate h-buffers (no aliasing -> only 2 barriers/tile).
// LDS: 3*6400 + 20480 + 10240 + 16 = 49936 B -> 3 blocks/CU.
__global__ __launch_bounds__(256, 3) void fuse_loss_kernel(
    const float* __restrict__ vis, const float* __restrict__ ir,
    const float* __restrict__ fus, const float* __restrict__ mask,
    float* __restrict__ ws, GaussW gw)
{
    __shared__ __align__(16) float s_ir[RH * RWE];
    __shared__ __align__(16) float s_vi[RH * RWE];
    __shared__ __align__(16) float s_fu[RH * RWE];
    __shared__ float4 s_h1[RH * TW];
    __shared__ float2 s_h2[RH * TW];
    __shared__ float s_part[4];

    const int t  = threadIdx.x;
    const int cx = t & 31;
    const int r0 = t >> 5;
    // staging chunk descriptors (tile-independent): 400 float4-chunks/plane-set
    const int c1 = t + 256;
    const int ry0 = t / 10,  p0 = t - ry0 * 10;
    const int ry1 = c1 / 10, p1 = c1 - ry1 * 10;
    const bool has1 = (t < 144);

    float acc = 0.f;
    int tile = blockIdx.x;

    Pref PA, PB;
    prefetch_tile(tile, cx, r0, has1, ry0, p0, ry1, p1, ir, vis, fus, mask, PA);

    #pragma unroll 1
    for (int it = 0; it < TPT; it += 2) {
        // ---- body 1: consume PA, prefetch PB ----
        int nt = tile + NBLK; if (nt >= NTILES) nt -= NTILES;
        stage_write(PA, has1, ry0, p0, ry1, p1, s_ir, s_vi, s_fu);
        prefetch_tile(nt, cx, r0, has1, ry0, p0, ry1, p1, ir, vis, fus, mask, PB);
        __syncthreads();
        phase_B(t, gw, s_ir, s_vi, s_fu, s_h1, s_h2);
        __syncthreads();
        phase_C(cx, r0, gw, PA, s_h1, s_h2, acc);
        tile = nt;

        // ---- body 2: consume PB, prefetch PA (skip last) ----
        nt = tile + NBLK; if (nt >= NTILES) nt -= NTILES;
        stage_write(PB, has1, ry0, p0, ry1, p1, s_ir, s_vi, s_fu);
        if (it + 2 < TPT)
            prefetch_tile(nt, cx, r0, has1, ry0, p0, ry1, p1, ir, vis, fus, mask, PA);
        __syncthreads();
        phase_B(t, gw, s_ir, s_vi, s_fu, s_h1, s_h2);
        __syncthreads();
        phase_C(cx, r0, gw, PB, s_h1, s_h2, acc);
        tile = nt;
    }

    // ---- one partial per block, no atomics ----
    #pragma unroll
    for (int off = 32; off > 0; off >>= 1)
        acc += __shfl_down(acc, off, 64);
    int wave = t >> 6, lane = t & 63;
    if (lane == 0) s_part[wave] = acc;
    __syncthreads();
    if (t == 0)
        ws[blockIdx.x] = s_part[0] + s_part[1] + s_part[2] + s_part[3];
}

__global__ __launch_bounds__(256) void reduce_kernel(const float* __restrict__ ws,
                                                     float* __restrict__ out)
{
    __shared__ float sp[4];
    int t = threadIdx.x;
    float v = 0.f;
    for (int i = t; i < NBLK; i += 256) v += ws[i];
    #pragma unroll
    for (int off = 32; off > 0; off >>= 1)
        v += __shfl_down(v, off, 64);
    if ((t & 63) == 0) sp[t >> 6] = v;
    __syncthreads();
    if (t == 0)
        out[0] = (sp[0] + sp[1] + sp[2] + sp[3]) * (1.f / ((float)Bn * Hn * Wn));
}

extern "C" void kernel_launch(void* const* d_in, const int* in_sizes, int n_in,
                              void* d_out, int out_size, void* d_ws, size_t ws_size,
                              hipStream_t stream) {
    const float* vis  = (const float*)d_in[0];
    const float* ir   = (const float*)d_in[1];
    const float* fus  = (const float*)d_in[2];
    const float* mask = (const float*)d_in[3];
    float* out = (float*)d_out;
    float* ws  = (float*)d_ws;

    GaussW gw;
    double g[9], s = 0.0;
    for (int i = 0; i < 9; ++i) {
        int x = i - 4;
        g[i] = exp(-(double)(x * x) / 4.5);
        s += g[i];
    }
    for (int i = 0; i < 9; ++i) gw.g[i] = (float)(g[i] / s);

    fuse_loss_kernel<<<NBLK, 256, 0, stream>>>(vis, ir, fus, mask, ws, gw);
    reduce_kernel<<<1, 256, 0, stream>>>(ws, out);
}

// Round 11
// 128.382 us; speedup vs baseline: 1.1251x; 1.1251x over previous
//
#include <hip/hip_runtime.h>
#include <cmath>

#define Bn 32
#define Hn 512
#define Wn 512
#define TW 32
#define TH 32
#define RH 40
#define RWE 44                        // padded plane row stride (floats): bank-quad shift 3/row
#define HS 33                         // padded h-buffer row stride (float4/float2 units)
#define NTILES 8192
#define NBLK 1024
#define TPT (NTILES / NBLK)           // 8 tiles per block

struct GaussW { float g[9]; };

// single-buffer cross-tile prefetch set (registers); ~30 VGPRs
struct Pref {
    float4 i0, v0, f0;    // chunk 0: ir, vis, fus
    float4 i1, v1, f1;    // chunk 1 (threads t<144 only)
    float mk0, mk1, mk2, mk3;
    int ok0, ok1;
};

__device__ __forceinline__ void prefetch_tile(
    int tile, int cx, int r0, bool has1,
    int ry0, int p0, int ry1, int p1,
    const float* __restrict__ ir, const float* __restrict__ vis,
    const float* __restrict__ fus, const float* __restrict__ mask,
    Pref& P)
{
    const int rem = tile & 255;
    const int y0 = (rem >> 4) * TH;
    const int x0 = (rem & 15) * TW;
    const size_t base = (size_t)(tile >> 8) * (size_t)(Hn * Wn);

    // halo = 4 px = exactly one float4 -> chunks are all-or-nothing valid
    int gy0 = y0 + ry0 - 4, gx0 = x0 + p0 * 4 - 4;
    P.ok0 = ((unsigned)gy0 < (unsigned)Hn) &&
            !((x0 == 0) && (p0 == 0)) && !((x0 == Wn - TW) && (p0 == 9));
    size_t o0 = P.ok0 ? (base + (size_t)gy0 * Wn + gx0) : 0;
    P.i0 = *(const float4*)(ir + o0);
    P.v0 = *(const float4*)(vis + o0);
    P.f0 = *(const float4*)(fus + o0);

    int gy1 = y0 + ry1 - 4, gx1 = x0 + p1 * 4 - 4;
    P.ok1 = has1 && ((unsigned)gy1 < (unsigned)Hn) &&
            !((x0 == 0) && (p1 == 0)) && !((x0 == Wn - TW) && (p1 == 9));
    size_t o1 = P.ok1 ? (base + (size_t)gy1 * Wn + gx1) : 0;
    P.i1 = *(const float4*)(ir + o1);
    P.v1 = *(const float4*)(vis + o1);
    P.f1 = *(const float4*)(fus + o1);

    // mask for this thread's 4 output pixels (rows 4*r0+k, col cx)
    const size_t mb = base + (size_t)(y0 + 4 * r0) * Wn + (x0 + cx);
    P.mk0 = mask[mb];
    P.mk1 = mask[mb + Wn];
    P.mk2 = mask[mb + 2 * Wn];
    P.mk3 = mask[mb + 3 * Wn];
}

__device__ __forceinline__ void stage_write(
    const Pref& P, bool has1, int ry0, int p0, int ry1, int p1,
    float* s_ir, float* s_vi, float* s_fu)
{
    const float4 z = make_float4(0.f, 0.f, 0.f, 0.f);
    int d0 = ry0 * RWE + p0 * 4;
    *(float4*)&s_ir[d0] = P.ok0 ? P.i0 : z;
    *(float4*)&s_vi[d0] = P.ok0 ? P.v0 : z;
    *(float4*)&s_fu[d0] = P.ok0 ? P.f0 : z;
    if (has1) {
        int d1 = ry1 * RWE + p1 * 4;
        *(float4*)&s_ir[d1] = P.ok1 ? P.i1 : z;
        *(float4*)&s_vi[d1] = P.ok1 ? P.v1 : z;
        *(float4*)&s_fu[d1] = P.ok1 ? P.f1 : z;
    }
}

__device__ __forceinline__ void phase_B(
    int t, const GaussW& gw,
    const float* s_ir, const float* s_vi, const float* s_fu,
    float4* s_h1, float2* s_h2)
{
    // 320 tasks: (row ry 0..39) x (col-group g 0..7); 4 h-pixels per task
    for (int task = t; task < 320; task += 256) {
        int ry = task >> 3, g = task & 7;
        int fo = ry * RWE + g * 4;
        float4 A0 = *(const float4*)&s_ir[fo];
        float4 A1 = *(const float4*)&s_ir[fo + 4];
        float4 A2 = *(const float4*)&s_ir[fo + 8];
        float4 F0 = *(const float4*)&s_fu[fo];
        float4 F1 = *(const float4*)&s_fu[fo + 4];
        float4 F2 = *(const float4*)&s_fu[fo + 8];
        float4 V0 = *(const float4*)&s_vi[fo];
        float4 V1 = *(const float4*)&s_vi[fo + 4];
        float4 V2 = *(const float4*)&s_vi[fo + 8];
        float ira[12] = {A0.x,A0.y,A0.z,A0.w, A1.x,A1.y,A1.z,A1.w, A2.x,A2.y,A2.z,A2.w};
        float fua[12] = {F0.x,F0.y,F0.z,F0.w, F1.x,F1.y,F1.z,F1.w, F2.x,F2.y,F2.z,F2.w};
        float via[12] = {V0.x,V0.y,V0.z,V0.w, V1.x,V1.y,V1.z,V1.w, V2.x,V2.y,V2.z,V2.w};
        #pragma unroll
        for (int m = 0; m < 4; ++m) {
            float hbi = 0.f, hbv = 0.f, hgi = 0.f, hgv = 0.f, h2i = 0.f, h2v = 0.f;
            #pragma unroll
            for (int dx = 0; dx < 9; ++dx) {
                float a = ira[m + dx], f = fua[m + dx], v = via[m + dx];
                float di = a - f, dv = v - f;
                hbi = fmaf(di, di, hbi);
                hbv = fmaf(dv, dv, hbv);
                float gg = gw.g[dx];
                hgi = fmaf(gg, a, hgi);
                hgv = fmaf(gg, v, hgv);
                h2i = fmaf(gg, a * a, h2i);
                h2v = fmaf(gg, v * v, h2v);
            }
            int ho = ry * HS + g * 4 + m;
            s_h1[ho] = make_float4(hbi, hbv, hgi, hgv);
            s_h2[ho] = make_float2(h2i, h2v);
        }
    }
}

__device__ __forceinline__ void phase_C(
    int cx, int r0, const GaussW& gw,
    float mk0, float mk1, float mk2, float mk3,
    const float4* s_h1, const float2* s_h2, float& acc)
{
    // thread -> 4 consecutive output rows 4*r0+k at column cx; 12 shared taps
    float bi[4] = {0,0,0,0}, bv[4] = {0,0,0,0};
    float mi[4] = {0,0,0,0}, mv[4] = {0,0,0,0};
    float qi[4] = {0,0,0,0}, qv[4] = {0,0,0,0};
    int hb = (r0 * 4) * HS + cx;
    #pragma unroll
    for (int j = 0; j < 12; ++j) {
        float4 h1 = s_h1[hb + j * HS];
        float2 h2 = s_h2[hb + j * HS];
        #pragma unroll
        for (int k = 0; k < 4; ++k) {
            int d = j - k;
            if (d >= 0 && d <= 8) {       // compile-time predicate
                float gg = gw.g[d];
                bi[k] += h1.x;  bv[k] += h1.y;
                mi[k] = fmaf(gg, h1.z, mi[k]);
                mv[k] = fmaf(gg, h1.w, mv[k]);
                qi[k] = fmaf(gg, h2.x, qi[k]);
                qv[k] = fmaf(gg, h2.y, qv[k]);
            }
        }
    }
    #pragma unroll
    for (int k = 0; k < 4; ++k) {
        float var_i = qi[k] - mi[k] * mi[k];
        float var_v = qv[k] - mv[k] * mv[k];
        float m1 = (var_i - var_v > 0.f) ? 1.f : 0.f;
        float mkv = (k == 0) ? mk0 : (k == 1) ? mk1 : (k == 2) ? mk2 : mk3;
        float sel = (m1 + mkv > 0.f) ? 1.f : 0.f;
        acc += sel * (bi[k] * (1.f / 81.f)) + (1.f - sel) * (bv[k] * (1.f / 81.f));
    }
}

// SoA planes (padded RWE=44) + separate padded h-buffers; 2 barriers/tile.
// LDS: 3*7040 + 21120 + 10560 + 16 = 52816 B.
// launch_bounds(256,2): 128-VGPR budget -- R4/R10 showed arg>=3 (<=85 VGPR)
// spills this structure (WRITE_SIZE 0.25->284MB). Single-buffer Pref (~30
// regs) + working set ~100 fits 128 clean.
__global__ __launch_bounds__(256, 2) void fuse_loss_kernel(
    const float* __restrict__ vis, const float* __restrict__ ir,
    const float* __restrict__ fus, const float* __restrict__ mask,
    float* __restrict__ ws, GaussW gw)
{
    __shared__ __align__(16) float s_ir[RH * RWE];
    __shared__ __align__(16) float s_vi[RH * RWE];
    __shared__ __align__(16) float s_fu[RH * RWE];
    __shared__ float4 s_h1[RH * HS];
    __shared__ float2 s_h2[RH * HS];
    __shared__ float s_part[4];

    const int t  = threadIdx.x;
    const int cx = t & 31;
    const int r0 = t >> 5;
    // staging chunk descriptors (tile-independent): 400 float4-chunks/plane-set
    const int c1 = t + 256;
    const int ry0 = t / 10,  p0 = t - ry0 * 10;
    const int ry1 = c1 / 10, p1 = c1 - ry1 * 10;
    const bool has1 = (t < 144);

    float acc = 0.f;
    int tile = blockIdx.x;

    Pref PA;
    prefetch_tile(tile, cx, r0, has1, ry0, p0, ry1, p1, ir, vis, fus, mask, PA);

    #pragma unroll 1
    for (int it = 0; it < TPT; ++it) {
        int nt = tile + NBLK; if (nt >= NTILES) nt -= NTILES;

        stage_write(PA, has1, ry0, p0, ry1, p1, s_ir, s_vi, s_fu);
        // keep this tile's mask values; PA gets reused for the next prefetch
        float mk0 = PA.mk0, mk1 = PA.mk1, mk2 = PA.mk2, mk3 = PA.mk3;
        __syncthreads();                       // staging visible to all

        if (it + 1 < TPT)                      // issue next tile's loads now;
            prefetch_tile(nt, cx, r0, has1,    // in flight across B + C
                          ry0, p0, ry1, p1, ir, vis, fus, mask, PA);

        phase_B(t, gw, s_ir, s_vi, s_fu, s_h1, s_h2);
        __syncthreads();                       // h-buffers complete

        phase_C(cx, r0, gw, mk0, mk1, mk2, mk3, s_h1, s_h2, acc);
        // no barrier needed: next stage_write touches planes only, disjoint
        // from s_h read by phase_C; sync1 of next iter orders plane reads.
        tile = nt;
    }

    // ---- one partial per block, no atomics ----
    #pragma unroll
    for (int off = 32; off > 0; off >>= 1)
        acc += __shfl_down(acc, off, 64);
    int wave = t >> 6, lane = t & 63;
    if (lane == 0) s_part[wave] = acc;
    __syncthreads();
    if (t == 0)
        ws[blockIdx.x] = s_part[0] + s_part[1] + s_part[2] + s_part[3];
}

__global__ __launch_bounds__(256) void reduce_kernel(const float* __restrict__ ws,
                                                     float* __restrict__ out)
{
    __shared__ float sp[4];
    int t = threadIdx.x;
    float v = 0.f;
    for (int i = t; i < NBLK; i += 256) v += ws[i];
    #pragma unroll
    for (int off = 32; off > 0; off >>= 1)
        v += __shfl_down(v, off, 64);
    if ((t & 63) == 0) sp[t >> 6] = v;
    __syncthreads();
    if (t == 0)
        out[0] = (sp[0] + sp[1] + sp[2] + sp[3]) * (1.f / ((float)Bn * Hn * Wn));
}

extern "C" void kernel_launch(void* const* d_in, const int* in_sizes, int n_in,
                              void* d_out, int out_size, void* d_ws, size_t ws_size,
                              hipStream_t stream) {
    const float* vis  = (const float*)d_in[0];
    const float* ir   = (const float*)d_in[1];
    const float* fus  = (const float*)d_in[2];
    const float* mask = (const float*)d_in[3];
    float* out = (float*)d_out;
    float* ws  = (float*)d_ws;

    GaussW gw;
    double g[9], s = 0.0;
    for (int i = 0; i < 9; ++i) {
        int x = i - 4;
        g[i] = exp(-(double)(x * x) / 4.5);
        s += g[i];
    }
    for (int i = 0; i < 9; ++i) gw.g[i] = (float)(g[i] / s);

    fuse_loss_kernel<<<NBLK, 256, 0, stream>>>(vis, ir, fus, mask, ws, gw);
    reduce_kernel<<<1, 256, 0, stream>>>(ws, out);
}

// Round 12
// 91.932 us; speedup vs baseline: 1.5712x; 1.3965x over previous
//
#include <hip/hip_runtime.h>
#include <cmath>

#define Bn 32
#define Hn 512
#define Wn 512
#define PADn 4
#define TW 32
#define TH 32
#define RW (TW + 8)   // 40
#define RH (TH + 8)   // 40
#define NPTS (RH * RW)                         // 1600 staged points
#define NTILES (Bn * (Hn / TH) * (Wn / TW))   // 8192
#define NBLK 1024                              // persistent blocks; 8 tiles each

struct GaussW { float g[9]; };

// R8 structure (best clean: 91.3us, 108 VGPR, no spill) with the
// waves-per-EU hint REMOVED: cross-round evidence (R4=4->42%, R5/R8=2->20%,
// R10=3->26%) says launch_bounds arg2 was capping residency at ~arg2
// waves/EU while raising it shrank the VGPR budget below the ~100-reg
// working set (spill). No hint: allocator sizes to code, HW fills to the
// true static limit (VGPR 108 -> 4 blocks/CU; LDS 31KB -> 5).
__global__ __launch_bounds__(256) void fuse_loss_kernel(
    const float* __restrict__ vis, const float* __restrict__ ir,
    const float* __restrict__ fus, const float* __restrict__ mask,
    float* __restrict__ ws, GaussW gw)
{
    // Union LDS: phase A/B use s_in[40][40] float4 (25600 B); after a barrier
    // reused as s_h1[40][32] float4 (20480 B) + s_h2[40][32] float2 (10240 B).
    __shared__ float4 s_buf[1920];          // 30720 B
    float4* s_in = s_buf;                   // [RH][RW]
    float4* s_h1 = s_buf;                   // [RH][TW]
    float2* s_h2 = (float2*)(s_buf + 1280); // [RH][TW]
    __shared__ float s_part[4];

    const int t  = threadIdx.x;
    const int cx = t & 31;      // column owned by this thread (phases B & C)
    const int r0 = t >> 5;      // base row

    float acc = 0.f;            // across all tiles this block owns

    for (int tile = blockIdx.x; tile < NTILES; tile += NBLK) {
        const int img = tile >> 8;          // 256 tiles per image
        const int rem = tile & 255;
        const int y0 = (rem >> 4) * TH;
        const int x0 = (rem & 15) * TW;
        const size_t base = (size_t)img * (size_t)(Hn * Wn);

        // ---- Phase A: issue-early register staging (21 loads in flight) ----
        float vir[7], vvi[7], vfu[7];
        bool  okf[7];
        #pragma unroll
        for (int r = 0; r < 7; ++r) {
            int idx = t + 256 * r;
            int ry = idx / RW, rx = idx - ry * RW;
            int gy = y0 + ry - PADn, gx = x0 + rx - PADn;
            bool ok = (idx < NPTS) &&
                      ((unsigned)gy < (unsigned)Hn) && ((unsigned)gx < (unsigned)Wn);
            size_t o = ok ? (base + (size_t)gy * Wn + gx) : 0;
            vir[r] = ir[o];            // predicated via clamped addr + select
            vvi[r] = vis[o];
            vfu[r] = fus[o];
            okf[r] = ok;
        }
        // prefetch mask for this thread's 4 output pixels (also in flight)
        float mk[4];
        #pragma unroll
        for (int k = 0; k < 4; ++k) {
            int ty = r0 + 8 * k;
            mk[k] = mask[base + (size_t)(y0 + ty) * Wn + (x0 + cx)];
        }
        // write-late: one waitcnt, then stream all stores to LDS
        #pragma unroll
        for (int r = 0; r < 7; ++r) {
            int idx = t + 256 * r;
            if (idx < NPTS) {
                float4 v = okf[r] ? make_float4(vir[r], vvi[r], vfu[r], 0.f)
                                  : make_float4(0.f, 0.f, 0.f, 0.f);
                s_in[idx] = v;
            }
        }
        __syncthreads();

        // ---- Phase B: horizontal 9-tap pass, results in registers ----
        float r_hb_ir[5], r_hb_vi[5], r_hg_ir[5], r_hg_vi[5], r_hg_i2[5], r_hg_v2[5];
        #pragma unroll
        for (int k = 0; k < 5; ++k) {
            int ry = r0 + 8 * k;
            float hb_ir = 0.f, hb_vi = 0.f;
            float hg_ir = 0.f, hg_vi = 0.f, hg_i2 = 0.f, hg_v2 = 0.f;
            #pragma unroll
            for (int dx = 0; dx < 9; ++dx) {
                float4 v = s_in[ry * RW + cx + dx];
                float di = v.x - v.z;
                float dv = v.y - v.z;
                hb_ir = fmaf(di, di, hb_ir);
                hb_vi = fmaf(dv, dv, hb_vi);
                float g = gw.g[dx];
                hg_ir = fmaf(g, v.x, hg_ir);
                hg_vi = fmaf(g, v.y, hg_vi);
                hg_i2 = fmaf(g, v.x * v.x, hg_i2);
                hg_v2 = fmaf(g, v.y * v.y, hg_v2);
            }
            r_hb_ir[k] = hb_ir; r_hb_vi[k] = hb_vi;
            r_hg_ir[k] = hg_ir; r_hg_vi[k] = hg_vi;
            r_hg_i2[k] = hg_i2; r_hg_v2[k] = hg_v2;
        }
        __syncthreads();   // all s_in reads complete -> safe to overwrite

        #pragma unroll
        for (int k = 0; k < 5; ++k) {
            int ry = r0 + 8 * k;
            s_h1[ry * TW + cx] = make_float4(r_hb_ir[k], r_hb_vi[k], r_hg_ir[k], r_hg_vi[k]);
            s_h2[ry * TW + cx] = make_float2(r_hg_i2[k], r_hg_v2[k]);
        }
        __syncthreads();

        // ---- Phase C: vertical 9-tap pass + selection + accumulate ----
        #pragma unroll
        for (int k = 0; k < 4; ++k) {
            int ty = r0 + 8 * k;
            float b_ir = 0.f, b_vi = 0.f;
            float mu_ir = 0.f, mu_vi = 0.f, m2_ir = 0.f, m2_vi = 0.f;
            #pragma unroll
            for (int dy = 0; dy < 9; ++dy) {
                float4 h1 = s_h1[(ty + dy) * TW + cx];
                float2 h2 = s_h2[(ty + dy) * TW + cx];
                b_ir += h1.x;
                b_vi += h1.y;
                float g = gw.g[dy];
                mu_ir = fmaf(g, h1.z, mu_ir);
                mu_vi = fmaf(g, h1.w, mu_vi);
                m2_ir = fmaf(g, h2.x, m2_ir);
                m2_vi = fmaf(g, h2.y, m2_vi);
            }
            float mse_ir = b_ir * (1.f / 81.f);
            float mse_vi = b_vi * (1.f / 81.f);
            float var_ir = m2_ir - mu_ir * mu_ir;
            float var_vi = m2_vi - mu_vi * mu_vi;
            float m1 = (var_ir - var_vi > 0.f) ? 1.f : 0.f;
            float mir = (m1 + mk[k] > 0.f) ? 1.f : 0.f;
            acc += mir * mse_ir + (1.f - mir) * mse_vi;
        }
        __syncthreads();   // s_h reads done -> next tile may overwrite s_in
    }

    // ---- one partial per block, no atomics ----
    #pragma unroll
    for (int off = 32; off > 0; off >>= 1)
        acc += __shfl_down(acc, off, 64);
    int wave = t >> 6, lane = t & 63;
    if (lane == 0) s_part[wave] = acc;
    __syncthreads();
    if (t == 0)
        ws[blockIdx.x] = s_part[0] + s_part[1] + s_part[2] + s_part[3];
}

__global__ __launch_bounds__(256) void reduce_kernel(const float* __restrict__ ws,
                                                     float* __restrict__ out)
{
    __shared__ float sp[4];
    int t = threadIdx.x;
    float v = 0.f;
    for (int i = t; i < NBLK; i += 256) v += ws[i];
    #pragma unroll
    for (int off = 32; off > 0; off >>= 1)
        v += __shfl_down(v, off, 64);
    if ((t & 63) == 0) sp[t >> 6] = v;
    __syncthreads();
    if (t == 0)
        out[0] = (sp[0] + sp[1] + sp[2] + sp[3]) * (1.f / ((float)Bn * Hn * Wn));
}

extern "C" void kernel_launch(void* const* d_in, const int* in_sizes, int n_in,
                              void* d_out, int out_size, void* d_ws, size_t ws_size,
                              hipStream_t stream) {
    const float* vis  = (const float*)d_in[0];
    const float* ir   = (const float*)d_in[1];
    const float* fus  = (const float*)d_in[2];
    const float* mask = (const float*)d_in[3];
    float* out = (float*)d_out;
    float* ws  = (float*)d_ws;

    GaussW gw;
    double g[9], s = 0.0;
    for (int i = 0; i < 9; ++i) {
        int x = i - 4;
        g[i] = exp(-(double)(x * x) / 4.5);
        s += g[i];
    }
    for (int i = 0; i < 9; ++i) gw.g[i] = (float)(g[i] / s);

    fuse_loss_kernel<<<NBLK, 256, 0, stream>>>(vis, ir, fus, mask, ws, gw);
    reduce_kernel<<<1, 256, 0, stream>>>(ws, out);
}

// Round 13
// 71.136 us; speedup vs baseline: 2.0306x; 1.2923x over previous
//
#include <hip/hip_runtime.h>
#include <cmath>

#define Bn 32
#define Hn 512
#define Wn 512
#define PADn 4
#define TW 32
#define TH 32
#define RH 40
#define RW 40
#define PS 43          // float2 plane row stride (bank-spread: 43 odd vs 16)
#define HS 33          // h-buffer row stride (float2 units)
#define NPTS (RH * RW)            // 1600
#define NTILES 8192
#define NBLK 1024
#define TPT (NTILES / NBLK)       // 8 tiles per block

struct GaussW { float g[9]; };

// R13: persistent blocks + derived-plane staging + sliding-window box +
// shared-tap phase C + cross-tile prefetch. VALU/LDS arithmetic (R12 pm):
// R8's 37us VALU-issue at 38% busy bounds dur ~90; this cuts instr ~40%
// (squares/diffs hoisted to staging; box h-pass telescoped; C taps shared
// 12->4px) and LDS reads ~50%. 2 barriers/tile. No launch_bounds arg2
// (R12: allocator alone picks ~108, no spill; arg>=3 spills ~100-reg set).
__global__ __launch_bounds__(256) void fuse_loss_kernel(
    const float* __restrict__ vis, const float* __restrict__ ir,
    const float* __restrict__ fus, const float* __restrict__ mask,
    float* __restrict__ ws, GaussW gw)
{
    __shared__ float2 s_av[RH * PS];   // (a, v)          13760 B
    __shared__ float2 s_sq[RH * PS];   // (a^2, v^2)      13760 B
    __shared__ float2 s_d [RH * PS];   // ((a-f)^2,(v-f)^2) 13760 B
    __shared__ float2 s_hb[RH * HS];   // h box sums      10560 B
    __shared__ float2 s_hg[RH * HS];   // h gauss (a,v)   10560 B
    __shared__ float2 s_hq[RH * HS];   // h gauss (a2,v2) 10560 B
    __shared__ float  s_part[4];       // total ~72.9 KB -> 2 blocks/CU

    const int t  = threadIdx.x;
    const int cx = t & 31;
    const int r0 = t >> 5;           // 0..7

    float acc = 0.f;
    float lir[7], lvi[7], lfu[7], lmk[4];

    // ---- prologue: issue tile-0 loads (clamped addr, zeroed at store) ----
    {
        const int tile = blockIdx.x;
        const int rem  = tile & 255;
        const int y0 = (rem >> 4) * TH, x0 = (rem & 15) * TW;
        const size_t base = (size_t)(tile >> 8) * (size_t)(Hn * Wn);
        #pragma unroll
        for (int r = 0; r < 7; ++r) {
            int idx = t + 256 * r;
            int ry = idx / RW, rx = idx - ry * RW;
            int gy = y0 + ry - PADn, gx = x0 + rx - PADn;
            bool ok = (idx < NPTS) && ((unsigned)gy < (unsigned)Hn) &&
                      ((unsigned)gx < (unsigned)Wn);
            size_t o = ok ? (base + (size_t)gy * Wn + gx) : 0;
            lir[r] = ir[o]; lvi[r] = vis[o]; lfu[r] = fus[o];
        }
        const size_t mb = base + (size_t)(y0 + 4 * r0) * Wn + (x0 + cx);
        lmk[0] = mask[mb];          lmk[1] = mask[mb + Wn];
        lmk[2] = mask[mb + 2 * Wn]; lmk[3] = mask[mb + 3 * Wn];
    }

    #pragma unroll 1
    for (int it = 0; it < TPT; ++it) {
        const int tile = blockIdx.x + it * NBLK;
        const int rem  = tile & 255;
        const int y0 = (rem >> 4) * TH, x0 = (rem & 15) * TW;

        // ---- A': derived values -> planes (validity recomputed) ----
        #pragma unroll
        for (int r = 0; r < 7; ++r) {
            int idx = t + 256 * r;
            if (idx < NPTS) {
                int ry = idx / RW, rx = idx - ry * RW;
                int gy = y0 + ry - PADn, gx = x0 + rx - PADn;
                bool ok = ((unsigned)gy < (unsigned)Hn) &&
                          ((unsigned)gx < (unsigned)Wn);
                float a = ok ? lir[r] : 0.f;
                float v = ok ? lvi[r] : 0.f;
                float f = ok ? lfu[r] : 0.f;
                float di = a - f, dv = v - f;
                int off = ry * PS + rx;
                s_av[off] = make_float2(a, v);
                s_sq[off] = make_float2(a * a, v * v);
                s_d [off] = make_float2(di * di, dv * dv);
            }
        }
        float cm0 = lmk[0], cm1 = lmk[1], cm2 = lmk[2], cm3 = lmk[3];
        __syncthreads();                          // planes ready

        // ---- issue next tile's loads; in flight across B + C ----
        if (it + 1 < TPT) {
            const int nt = tile + NBLK;
            const int nrem = nt & 255;
            const int ny0 = (nrem >> 4) * TH, nx0 = (nrem & 15) * TW;
            const size_t nbase = (size_t)(nt >> 8) * (size_t)(Hn * Wn);
            #pragma unroll
            for (int r = 0; r < 7; ++r) {
                int idx = t + 256 * r;
                int ry = idx / RW, rx = idx - ry * RW;
                int gy = ny0 + ry - PADn, gx = nx0 + rx - PADn;
                bool ok = (idx < NPTS) && ((unsigned)gy < (unsigned)Hn) &&
                          ((unsigned)gx < (unsigned)Wn);
                size_t o = ok ? (nbase + (size_t)gy * Wn + gx) : 0;
                lir[r] = ir[o]; lvi[r] = vis[o]; lfu[r] = fus[o];
            }
            const size_t mb = nbase + (size_t)(ny0 + 4 * r0) * Wn + (nx0 + cx);
            lmk[0] = mask[mb];          lmk[1] = mask[mb + Wn];
            lmk[2] = mask[mb + 2 * Wn]; lmk[3] = mask[mb + 3 * Wn];
        }

        // ---- B: horizontal pass, 4 adjacent cols per task ----
        #pragma unroll 1
        for (int task = t; task < 320; task += 256) {
            int ry = task >> 3, g = task & 7;
            int po = ry * PS + 4 * g;
            int ho = ry * HS + 4 * g;
            {   // box: sliding 9-wide sum of d-plane
                float2 d[12];
                #pragma unroll
                for (int j = 0; j < 12; ++j) d[j] = s_d[po + j];
                float si = ((d[0].x + d[1].x) + (d[2].x + d[3].x)) +
                           ((d[4].x + d[5].x) + (d[6].x + d[7].x)) + d[8].x;
                float sv = ((d[0].y + d[1].y) + (d[2].y + d[3].y)) +
                           ((d[4].y + d[5].y) + (d[6].y + d[7].y)) + d[8].y;
                s_hb[ho + 0] = make_float2(si, sv);
                si += d[9].x  - d[0].x;  sv += d[9].y  - d[0].y;
                s_hb[ho + 1] = make_float2(si, sv);
                si += d[10].x - d[1].x;  sv += d[10].y - d[1].y;
                s_hb[ho + 2] = make_float2(si, sv);
                si += d[11].x - d[2].x;  sv += d[11].y - d[2].y;
                s_hb[ho + 3] = make_float2(si, sv);
            }
            {   // gauss on (a, v)
                float2 w[12];
                #pragma unroll
                for (int j = 0; j < 12; ++j) w[j] = s_av[po + j];
                #pragma unroll
                for (int m = 0; m < 4; ++m) {
                    float ga = 0.f, gv = 0.f;
                    #pragma unroll
                    for (int dx = 0; dx < 9; ++dx) {
                        float gg = gw.g[dx];
                        ga = fmaf(gg, w[m + dx].x, ga);
                        gv = fmaf(gg, w[m + dx].y, gv);
                    }
                    s_hg[ho + m] = make_float2(ga, gv);
                }
            }
            {   // gauss on (a^2, v^2)
                float2 w[12];
                #pragma unroll
                for (int j = 0; j < 12; ++j) w[j] = s_sq[po + j];
                #pragma unroll
                for (int m = 0; m < 4; ++m) {
                    float ga = 0.f, gv = 0.f;
                    #pragma unroll
                    for (int dx = 0; dx < 9; ++dx) {
                        float gg = gw.g[dx];
                        ga = fmaf(gg, w[m + dx].x, ga);
                        gv = fmaf(gg, w[m + dx].y, gv);
                    }
                    s_hq[ho + m] = make_float2(ga, gv);
                }
            }
        }
        __syncthreads();                          // h ready

        // ---- C: vertical pass, 4 consecutive rows/thread, 12 shared taps ----
        {
            float bi[4] = {0,0,0,0}, bv[4] = {0,0,0,0};
            float mi[4] = {0,0,0,0}, mv[4] = {0,0,0,0};
            float qi[4] = {0,0,0,0}, qv[4] = {0,0,0,0};
            #pragma unroll
            for (int j = 0; j < 12; ++j) {
                int off = (4 * r0 + j) * HS + cx;
                float2 hb = s_hb[off];
                float2 hg = s_hg[off];
                float2 hq = s_hq[off];
                #pragma unroll
                for (int k = 0; k < 4; ++k) {
                    int d = j - k;
                    if (d >= 0 && d <= 8) {       // compile-time predicate
                        float gg = gw.g[d];
                        bi[k] += hb.x;  bv[k] += hb.y;
                        mi[k] = fmaf(gg, hg.x, mi[k]);
                        mv[k] = fmaf(gg, hg.y, mv[k]);
                        qi[k] = fmaf(gg, hq.x, qi[k]);
                        qv[k] = fmaf(gg, hq.y, qv[k]);
                    }
                }
            }
            #pragma unroll
            for (int k = 0; k < 4; ++k) {
                float var_i = qi[k] - mi[k] * mi[k];
                float var_v = qv[k] - mv[k] * mv[k];
                float m1  = (var_i - var_v > 0.f) ? 1.f : 0.f;
                float mkv = (k == 0) ? cm0 : (k == 1) ? cm1 : (k == 2) ? cm2 : cm3;
                float sel = (m1 + mkv > 0.f) ? 1.f : 0.f;
                acc += sel * (bi[k] * (1.f / 81.f)) +
                       (1.f - sel) * (bv[k] * (1.f / 81.f));
            }
        }
        // no 3rd barrier: next A' writes planes (disjoint from h-buffers
        // read by C); next B is ordered behind next bar1.
    }

    // ---- one partial per block, no atomics ----
    #pragma unroll
    for (int off = 32; off > 0; off >>= 1)
        acc += __shfl_down(acc, off, 64);
    int wave = t >> 6, lane = t & 63;
    if (lane == 0) s_part[wave] = acc;
    __syncthreads();
    if (t == 0)
        ws[blockIdx.x] = s_part[0] + s_part[1] + s_part[2] + s_part[3];
}

__global__ __launch_bounds__(256) void reduce_kernel(const float* __restrict__ ws,
                                                     float* __restrict__ out)
{
    __shared__ float sp[4];
    int t = threadIdx.x;
    float v = 0.f;
    for (int i = t; i < NBLK; i += 256) v += ws[i];
    #pragma unroll
    for (int off = 32; off > 0; off >>= 1)
        v += __shfl_down(v, off, 64);
    if ((t & 63) == 0) sp[t >> 6] = v;
    __syncthreads();
    if (t == 0)
        out[0] = (sp[0] + sp[1] + sp[2] + sp[3]) * (1.f / ((float)Bn * Hn * Wn));
}

extern "C" void kernel_launch(void* const* d_in, const int* in_sizes, int n_in,
                              void* d_out, int out_size, void* d_ws, size_t ws_size,
                              hipStream_t stream) {
    const float* vis  = (const float*)d_in[0];
    const float* ir   = (const float*)d_in[1];
    const float* fus  = (const float*)d_in[2];
    const float* mask = (const float*)d_in[3];
    float* out = (float*)d_out;
    float* ws  = (float*)d_ws;

    GaussW gw;
    double g[9], s = 0.0;
    for (int i = 0; i < 9; ++i) {
        int x = i - 4;
        g[i] = exp(-(double)(x * x) / 4.5);
        s += g[i];
    }
    for (int i = 0; i < 9; ++i) gw.g[i] = (float)(g[i] / s);

    fuse_loss_kernel<<<NBLK, 256, 0, stream>>>(vis, ir, fus, mask, ws, gw);
    reduce_kernel<<<1, 256, 0, stream>>>(ws, out);
}

// Round 14
// 61.838 us; speedup vs baseline: 2.3359x; 1.1504x over previous
//
#include <hip/hip_runtime.h>
#include <cmath>

#define Bn 32
#define Hn 512
#define Wn 512
#define PADn 4
#define TW 32
#define TH 32
#define RH 40
#define RW 40
#define PS 42          // av plane row stride (float2): even -> b128-aligned reads
#define FS 42          // f plane row stride (floats)
#define HS 33          // h-buffer row stride (float2 units)
#define NPTS (RH * RW)            // 1600
#define NTILES 8192
#define NBLK 1024
#define TPT (NTILES / NBLK)       // 8 tiles per block

struct GaussW { float g[9]; };

// R14: R13 minus two derived planes (sq, d recomputed in B from av+f).
// LDS 73.2KB -> 51.9KB crosses the 53.3KB boundary: 2 -> 3 blocks/CU.
// Even stride 42 makes B's av reads 6x ds_read_b128 (bank-balanced).
__global__ __launch_bounds__(256) void fuse_loss_kernel(
    const float* __restrict__ vis, const float* __restrict__ ir,
    const float* __restrict__ fus, const float* __restrict__ mask,
    float* __restrict__ ws, GaussW gw)
{
    __shared__ __align__(16) float2 s_av[RH * PS];   // (a, v)   13440 B
    __shared__ __align__(16) float  s_f [RH * FS];   // fuse      6720 B
    __shared__ float2 s_hb[RH * HS];                 // h box    10560 B
    __shared__ float2 s_hg[RH * HS];                 // h gauss  10560 B
    __shared__ float2 s_hq[RH * HS];                 // h gauss2 10560 B
    __shared__ float  s_part[4];                     // ~51.9 KB total

    const int t  = threadIdx.x;
    const int cx = t & 31;
    const int r0 = t >> 5;           // 0..7

    float acc = 0.f;
    float lir[7], lvi[7], lfu[7], lmk[4];

    // ---- prologue: issue tile-0 loads (clamped addr, zeroed at store) ----
    {
        const int tile = blockIdx.x;
        const int rem  = tile & 255;
        const int y0 = (rem >> 4) * TH, x0 = (rem & 15) * TW;
        const size_t base = (size_t)(tile >> 8) * (size_t)(Hn * Wn);
        #pragma unroll
        for (int r = 0; r < 7; ++r) {
            int idx = t + 256 * r;
            int ry = idx / RW, rx = idx - ry * RW;
            int gy = y0 + ry - PADn, gx = x0 + rx - PADn;
            bool ok = (idx < NPTS) && ((unsigned)gy < (unsigned)Hn) &&
                      ((unsigned)gx < (unsigned)Wn);
            size_t o = ok ? (base + (size_t)gy * Wn + gx) : 0;
            lir[r] = ir[o]; lvi[r] = vis[o]; lfu[r] = fus[o];
        }
        const size_t mb = base + (size_t)(y0 + 4 * r0) * Wn + (x0 + cx);
        lmk[0] = mask[mb];          lmk[1] = mask[mb + Wn];
        lmk[2] = mask[mb + 2 * Wn]; lmk[3] = mask[mb + 3 * Wn];
    }

    #pragma unroll 1
    for (int it = 0; it < TPT; ++it) {
        const int tile = blockIdx.x + it * NBLK;
        const int rem  = tile & 255;
        const int y0 = (rem >> 4) * TH, x0 = (rem & 15) * TW;

        // ---- A': raw values -> planes (validity recomputed) ----
        #pragma unroll
        for (int r = 0; r < 7; ++r) {
            int idx = t + 256 * r;
            if (idx < NPTS) {
                int ry = idx / RW, rx = idx - ry * RW;
                int gy = y0 + ry - PADn, gx = x0 + rx - PADn;
                bool ok = ((unsigned)gy < (unsigned)Hn) &&
                          ((unsigned)gx < (unsigned)Wn);
                float a = ok ? lir[r] : 0.f;
                float v = ok ? lvi[r] : 0.f;
                float f = ok ? lfu[r] : 0.f;
                s_av[ry * PS + rx] = make_float2(a, v);
                s_f [ry * FS + rx] = f;
            }
        }
        float cm0 = lmk[0], cm1 = lmk[1], cm2 = lmk[2], cm3 = lmk[3];
        __syncthreads();                          // planes ready

        // ---- issue next tile's loads; in flight across B + C ----
        if (it + 1 < TPT) {
            const int nt = tile + NBLK;
            const int nrem = nt & 255;
            const int ny0 = (nrem >> 4) * TH, nx0 = (nrem & 15) * TW;
            const size_t nbase = (size_t)(nt >> 8) * (size_t)(Hn * Wn);
            #pragma unroll
            for (int r = 0; r < 7; ++r) {
                int idx = t + 256 * r;
                int ry = idx / RW, rx = idx - ry * RW;
                int gy = ny0 + ry - PADn, gx = nx0 + rx - PADn;
                bool ok = (idx < NPTS) && ((unsigned)gy < (unsigned)Hn) &&
                          ((unsigned)gx < (unsigned)Wn);
                size_t o = ok ? (nbase + (size_t)gy * Wn + gx) : 0;
                lir[r] = ir[o]; lvi[r] = vis[o]; lfu[r] = fus[o];
            }
            const size_t mb = nbase + (size_t)(ny0 + 4 * r0) * Wn + (nx0 + cx);
            lmk[0] = mask[mb];          lmk[1] = mask[mb + Wn];
            lmk[2] = mask[mb + 2 * Wn]; lmk[3] = mask[mb + 3 * Wn];
        }

        // ---- B: horizontal pass, 4 adjacent cols per task ----
        #pragma unroll 1
        for (int task = t; task < 320; task += 256) {
            int ry = task >> 3, g = task & 7;
            int po = ry * PS + 4 * g;             // float2 idx, even
            int ho = ry * HS + 4 * g;

            float2 av[12];
            #pragma unroll
            for (int j = 0; j < 6; ++j)
                *(float4*)&av[2 * j] = *(const float4*)&s_av[po + 2 * j];
            float2 fv[6];
            {
                const float2* fp = (const float2*)s_f;
                int fo2 = (ry * FS + 4 * g) >> 1; // FS even, 4g even
                #pragma unroll
                for (int j = 0; j < 6; ++j) fv[j] = fp[fo2 + j];
            }

            {   // box: d^2 then sliding 9-wide sum
                float dI[12], dV[12];
                #pragma unroll
                for (int k = 0; k < 12; ++k) {
                    float f = (k & 1) ? fv[k >> 1].y : fv[k >> 1].x;
                    float di = av[k].x - f, dv = av[k].y - f;
                    dI[k] = di * di; dV[k] = dv * dv;
                }
                float si = ((dI[0] + dI[1]) + (dI[2] + dI[3])) +
                           ((dI[4] + dI[5]) + (dI[6] + dI[7])) + dI[8];
                float sv = ((dV[0] + dV[1]) + (dV[2] + dV[3])) +
                           ((dV[4] + dV[5]) + (dV[6] + dV[7])) + dV[8];
                s_hb[ho + 0] = make_float2(si, sv);
                si += dI[9]  - dI[0];  sv += dV[9]  - dV[0];
                s_hb[ho + 1] = make_float2(si, sv);
                si += dI[10] - dI[1];  sv += dV[10] - dV[1];
                s_hb[ho + 2] = make_float2(si, sv);
                si += dI[11] - dI[2];  sv += dV[11] - dV[2];
                s_hb[ho + 3] = make_float2(si, sv);
            }
            {   // gauss on (a,v) and (a^2,v^2)
                float sqI[12], sqV[12];
                #pragma unroll
                for (int k = 0; k < 12; ++k) {
                    sqI[k] = av[k].x * av[k].x;
                    sqV[k] = av[k].y * av[k].y;
                }
                #pragma unroll
                for (int m = 0; m < 4; ++m) {
                    float ga = 0.f, gv = 0.f, qa = 0.f, qv = 0.f;
                    #pragma unroll
                    for (int dx = 0; dx < 9; ++dx) {
                        float gg = gw.g[dx];
                        ga = fmaf(gg, av[m + dx].x, ga);
                        gv = fmaf(gg, av[m + dx].y, gv);
                        qa = fmaf(gg, sqI[m + dx], qa);
                        qv = fmaf(gg, sqV[m + dx], qv);
                    }
                    s_hg[ho + m] = make_float2(ga, gv);
                    s_hq[ho + m] = make_float2(qa, qv);
                }
            }
        }
        __syncthreads();                          // h ready

        // ---- C: vertical pass, 4 consecutive rows/thread, 12 shared taps ----
        {
            float bi[4] = {0,0,0,0}, bv[4] = {0,0,0,0};
            float mi[4] = {0,0,0,0}, mv[4] = {0,0,0,0};
            float qi[4] = {0,0,0,0}, qv[4] = {0,0,0,0};
            #pragma unroll
            for (int j = 0; j < 12; ++j) {
                int off = (4 * r0 + j) * HS + cx;
                float2 hb = s_hb[off];
                float2 hg = s_hg[off];
                float2 hq = s_hq[off];
                #pragma unroll
                for (int k = 0; k < 4; ++k) {
                    int d = j - k;
                    if (d >= 0 && d <= 8) {       // compile-time predicate
                        float gg = gw.g[d];
                        bi[k] += hb.x;  bv[k] += hb.y;
                        mi[k] = fmaf(gg, hg.x, mi[k]);
                        mv[k] = fmaf(gg, hg.y, mv[k]);
                        qi[k] = fmaf(gg, hq.x, qi[k]);
                        qv[k] = fmaf(gg, hq.y, qv[k]);
                    }
                }
            }
            #pragma unroll
            for (int k = 0; k < 4; ++k) {
                float var_i = qi[k] - mi[k] * mi[k];
                float var_v = qv[k] - mv[k] * mv[k];
                float m1  = (var_i - var_v > 0.f) ? 1.f : 0.f;
                float mkv = (k == 0) ? cm0 : (k == 1) ? cm1 : (k == 2) ? cm2 : cm3;
                float sel = (m1 + mkv > 0.f) ? 1.f : 0.f;
                acc += sel * (bi[k] * (1.f / 81.f)) +
                       (1.f - sel) * (bv[k] * (1.f / 81.f));
            }
        }
        // no 3rd barrier: next A' writes planes (disjoint from h-buffers
        // read by C); next B is ordered behind next bar1.
    }

    // ---- one partial per block, no atomics ----
    #pragma unroll
    for (int off = 32; off > 0; off >>= 1)
        acc += __shfl_down(acc, off, 64);
    int wave = t >> 6, lane = t & 63;
    if (lane == 0) s_part[wave] = acc;
    __syncthreads();
    if (t == 0)
        ws[blockIdx.x] = s_part[0] + s_part[1] + s_part[2] + s_part[3];
}

__global__ __launch_bounds__(256) void reduce_kernel(const float* __restrict__ ws,
                                                     float* __restrict__ out)
{
    __shared__ float sp[4];
    int t = threadIdx.x;
    float v = 0.f;
    for (int i = t; i < NBLK; i += 256) v += ws[i];
    #pragma unroll
    for (int off = 32; off > 0; off >>= 1)
        v += __shfl_down(v, off, 64);
    if ((t & 63) == 0) sp[t >> 6] = v;
    __syncthreads();
    if (t == 0)
        out[0] = (sp[0] + sp[1] + sp[2] + sp[3]) * (1.f / ((float)Bn * Hn * Wn));
}

extern "C" void kernel_launch(void* const* d_in, const int* in_sizes, int n_in,
                              void* d_out, int out_size, void* d_ws, size_t ws_size,
                              hipStream_t stream) {
    const float* vis  = (const float*)d_in[0];
    const float* ir   = (const float*)d_in[1];
    const float* fus  = (const float*)d_in[2];
    const float* mask = (const float*)d_in[3];
    float* out = (float*)d_out;
    float* ws  = (float*)d_ws;

    GaussW gw;
    double g[9], s = 0.0;
    for (int i = 0; i < 9; ++i) {
        int x = i - 4;
        g[i] = exp(-(double)(x * x) / 4.5);
        s += g[i];
    }
    for (int i = 0; i < 9; ++i) gw.g[i] = (float)(g[i] / s);

    fuse_loss_kernel<<<NBLK, 256, 0, stream>>>(vis, ir, fus, mask, ws, gw);
    reduce_kernel<<<1, 256, 0, stream>>>(ws, out);
}